// Round 3
// baseline (279.112 us; speedup 1.0000x reference)
//
#include <hip/hip_runtime.h>

#define MAXN 2048
#define ROWS_PER_WAVE 4

// Builds the deduplicated selection maps, exactly mirroring _fix_duplicates:
//   sel[j]   = rint(clip(w[j], 0, n-1))                 (round-half-even, like jnp.round)
//   dup[j]   = sel[j] seen at an earlier index
//   empties  = values never selected, consumed in DESCENDING order by dup rank
// block 0 -> column map (n=C), block 1 -> row map (n=R)
__global__ void build_map_kernel(const float* __restrict__ wc, const float* __restrict__ wr,
                                 int C, int R,
                                 int* __restrict__ colmap, int* __restrict__ rowmap) {
    const float* w;
    int n;
    int* outmap;
    if (blockIdx.x == 0) { w = wc; n = C; outmap = colmap; }
    else                 { w = wr; n = R; outmap = rowmap; }

    __shared__ int sel[MAXN];
    __shared__ int first[MAXN];
    __shared__ int emptyslot[MAXN];
    __shared__ int dts[256], ets[256];

    const int t = threadIdx.x;
    const int base = t * 8;           // contiguous 8-element segment per thread
    const float upper = (float)(n - 1);

    for (int k = 0; k < 8; k++) {
        int idx = base + k;
        if (idx < n) {
            float v = w[idx];
            v = fminf(fmaxf(v, 0.0f), upper);
            sel[idx]   = (int)rintf(v);      // RNE == jnp.round
            first[idx] = 0x7fffffff;
        }
    }
    __syncthreads();
    for (int k = 0; k < 8; k++) {
        int idx = base + k;
        if (idx < n) atomicMin(&first[sel[idx]], idx);
    }
    __syncthreads();

    int dflag[8], eflag[8];
    int dsum = 0, esum = 0;
    for (int k = 0; k < 8; k++) {
        int idx = base + k;
        if (idx < n) {
            dflag[k] = (first[sel[idx]] != idx) ? 1 : 0;   // non-first occurrence
            eflag[k] = (first[idx] == 0x7fffffff) ? 1 : 0; // value idx never used
        } else { dflag[k] = 0; eflag[k] = 0; }
        dsum += dflag[k]; esum += eflag[k];
    }

    // block-wide inclusive scans (Hillis-Steele over 256 per-thread sums)
    dts[t] = dsum; ets[t] = esum;
    __syncthreads();
    for (int off = 1; off < 256; off <<= 1) {
        int dv = 0, ev = 0;
        if (t >= off) { dv = dts[t - off]; ev = ets[t - off]; }
        __syncthreads();
        dts[t] += dv; ets[t] += ev;
        __syncthreads();
    }
    const int dexc = dts[t] - dsum;   // dups before my segment
    const int eexc = ets[t] - esum;   // empties (by value) below my segment
    const int E    = ets[255];        // total empties (== total dups)

    // scatter empties: value v with (# empties < v) = p goes to slot E-1-p (descending order)
    int erun = eexc;
    for (int k = 0; k < 8; k++) {
        int idx = base + k;
        if (idx < n && eflag[k]) emptyslot[E - 1 - erun] = idx;
        erun += eflag[k];
    }
    __syncthreads();

    // final map: k-th duplicate (index order) takes emptyslot[k]
    int drun = dexc;
    for (int k = 0; k < 8; k++) {
        int idx = base + k;
        if (idx < n) outmap[idx] = dflag[k] ? emptyslot[drun] : sel[idx];
        drun += dflag[k];
    }
}

// out[b, i, j] = x[b, rowmap[i], colmap[j]]
// Barrier-free software pipeline: 2 waves/block, each wave owns a private 8 KB
// LDS row buffer and processes ROWS_PER_WAVE consecutive output rows:
//   ds_write row k (per-wave DS ops are in-order -> no fence vs row k-1's reads)
//   issue row k+1 global loads (fly during the gather)
//   gather + store row k
// 16 KB LDS/block -> 10 blocks/CU by LDS; grid sized so all blocks are resident.
__global__ __launch_bounds__(128) void gather_kernel(
        const float* __restrict__ x,
        const int* __restrict__ rowmap,
        const int* __restrict__ colmap,
        float* __restrict__ out,
        int R, int C, int total) {
    __shared__ float lds[2 * MAXN];          // 2 waves x 8 KB
    const int wave = threadIdx.x >> 6;
    const int lane = threadIdx.x & 63;
    float* wlds = lds + wave * MAXN;
    const int wid  = blockIdx.x * 2 + wave;
    const int row0 = wid * ROWS_PER_WAVE;
    if (row0 >= total) return;

    const int n4 = C >> 2;                   // 512 float4 per row
    const int4* __restrict__ cmap4 = (const int4*)colmap;

    float4 v[8];
    // prologue: issue loads for the first row
    {
        const int b = row0 / R, i = row0 - b * R;
        const float4* __restrict__ src4 =
            (const float4*)(x + ((size_t)b * R + rowmap[i]) * (size_t)C);
        #pragma unroll
        for (int k = 0; k < 8; k++) {
            int idx = lane + 64 * k;
            if (idx < n4) v[k] = src4[idx];
        }
    }

    for (int r = 0; r < ROWS_PER_WAVE; r++) {
        const int row = row0 + r;
        if (row >= total) break;

        // commit staged row to this wave's LDS buffer (compiler waits vmcnt here)
        #pragma unroll
        for (int k = 0; k < 8; k++) {
            int idx = lane + 64 * k;
            if (idx < n4) ((float4*)wlds)[idx] = v[k];
        }

        // issue next row's global loads; they fly during the gather below
        if (r + 1 < ROWS_PER_WAVE && row + 1 < total) {
            const int nrow = row + 1;
            const int b = nrow / R, i = nrow - b * R;
            const float4* __restrict__ src4 =
                (const float4*)(x + ((size_t)b * R + rowmap[i]) * (size_t)C);
            #pragma unroll
            for (int k = 0; k < 8; k++) {
                int idx = lane + 64 * k;
                if (idx < n4) v[k] = src4[idx];
            }
        }

        // gather + store current row (cmap4 is L1-hot: 8 KB shared by the CU)
        float4* __restrict__ dst4 = (float4*)(out + (size_t)row * (size_t)C);
        #pragma unroll
        for (int k = 0; k < 8; k++) {
            int idx = lane + 64 * k;
            if (idx < n4) {
                int4 c = cmap4[idx];
                float4 o;
                o.x = wlds[c.x]; o.y = wlds[c.y]; o.z = wlds[c.z]; o.w = wlds[c.w];
                dst4[idx] = o;
            }
        }
    }
}

extern "C" void kernel_launch(void* const* d_in, const int* in_sizes, int n_in,
                              void* d_out, int out_size, void* d_ws, size_t ws_size,
                              hipStream_t stream) {
    const float* x  = (const float*)d_in[0];
    const float* wc = (const float*)d_in[1];
    const float* wr = (const float*)d_in[2];
    const int C = in_sizes[1];            // 2048
    const int R = in_sizes[2];            // 1024
    const int B = in_sizes[0] / (R * C);  // 16

    int* colmap = (int*)d_ws;
    int* rowmap = colmap + C;

    const int total = B * R;              // 16384 output rows
    const int rows_per_block = 2 * ROWS_PER_WAVE;
    const int nblocks = (total + rows_per_block - 1) / rows_per_block;  // 2048

    build_map_kernel<<<2, 256, 0, stream>>>(wc, wr, C, R, colmap, rowmap);
    gather_kernel<<<nblocks, 128, 0, stream>>>(x, rowmap, colmap,
                                               (float*)d_out, R, C, total);
}